// Round 1
// baseline (478.620 us; speedup 1.0000x reference)
//
#include <hip/hip_runtime.h>
#include <hip/hip_bf16.h>
#include <math.h>

#define BB 64
#define NN 320
#define NT 256
#define NV 32
#define NA 32
#define HIDD 512
#define NHEAD 8
#define FD 64

#define LDK 40    // GEMM LDS k-stride (bf16 units)

typedef __attribute__((ext_vector_type(8))) short bf16x8;
typedef __attribute__((ext_vector_type(4))) float floatx4;

__device__ __forceinline__ void split1(float v, unsigned short& h, unsigned short& l) {
    unsigned u = __float_as_uint(v);
    unsigned hu = u & 0xFFFF0000u;
    float lf = v - __uint_as_float(hu);
    h = (unsigned short)(hu >> 16);
    l = (unsigned short)(__float_as_uint(lf) >> 16);
}
__device__ __forceinline__ unsigned pack2(unsigned short a, unsigned short b) {
    return (unsigned)a | ((unsigned)b << 16);
}

// ---------------------------------------------------------------------------
// Split-bf16 MFMA GEMM. C[M,512] = A[M,K] @ B[K,512], 3-pass hi/lo.
// 128x128 tile, BK=32, 4 waves each 64x64.
// b_mode 0 (projections): epilogue writes fp32 x with batch/node remap.
// b_mode 1 (gemm_h): B = Wg_l [head][d][f]; epilogue writes Ht split-bf16
//   hi/lo DIRECTLY in MFMA B-fragment layout:
//   Ht[slab=b*8+hd][ks=j>>5][nt=f>>4][lane=(f&15)|(((j>>3)&3)<<4)][e=j&7]
//   (so attn loads B-frags as contiguous 16B per lane). No fp32 C written.
// ---------------------------------------------------------------------------
__global__ __launch_bounds__(256) void gemm_mfma(
    const float* __restrict__ A, const float* __restrict__ Bsrc,
    float* __restrict__ C, unsigned short* __restrict__ Hthi,
    unsigned short* __restrict__ Htlo, int M, int K, int b_mode, int rpb, int noff)
{
    __shared__ unsigned short Ah[128 * LDK];
    __shared__ unsigned short Al[128 * LDK];
    __shared__ unsigned short Bh[128 * LDK];
    __shared__ unsigned short Bl[128 * LDK];

    const int tid  = threadIdx.x;
    const int lane = tid & 63;
    const int w    = tid >> 6;
    const int rw   = w >> 1, cw = w & 1;
    const int m0   = blockIdx.x * 128;
    const int n0   = blockIdx.y * 128;

    floatx4 acc[4][4];
#pragma unroll
    for (int s = 0; s < 4; s++)
#pragma unroll
        for (int t = 0; t < 4; t++) acc[s][t] = (floatx4)0.f;

    const int arow = tid >> 1;
    const int akh  = (tid & 1) * 16;
    const int bc   = tid & 127;
    const int bkh  = (tid >> 7) * 16;
    const int bhead = (n0 + bc) >> 6;
    const int bf    = (n0 + bc) & 63;

    const int afrag0 = (rw * 64 + (lane & 15)) * LDK + (lane >> 4) * 8;
    const int bfrag0 = (cw * 64 + (lane & 15)) * LDK + (lane >> 4) * 8;

    for (int k0 = 0; k0 < K; k0 += 32) {
        __syncthreads();
        {
            const float* ga = A + (size_t)(m0 + arow) * K + k0 + akh;
            const int la = arow * LDK + akh;
            if (k0 + 32 <= K) {
#pragma unroll
                for (int u = 0; u < 4; u++) {
                    float4 v = *(const float4*)(ga + 4 * u);
                    unsigned short h0,h1,h2,h3,l0,l1,l2,l3;
                    split1(v.x,h0,l0); split1(v.y,h1,l1);
                    split1(v.z,h2,l2); split1(v.w,h3,l3);
                    *(uint2*)&Ah[la + 4*u] = make_uint2(pack2(h0,h1), pack2(h2,h3));
                    *(uint2*)&Al[la + 4*u] = make_uint2(pack2(l0,l1), pack2(l2,l3));
                }
            } else {
#pragma unroll
                for (int u = 0; u < 16; u++) {
                    float v = (k0 + akh + u < K) ? ga[u] : 0.f;
                    unsigned short h, l; split1(v, h, l);
                    Ah[la + u] = h; Al[la + u] = l;
                }
            }
        }
        {
            unsigned short hb[16], lb[16];
#pragma unroll
            for (int u = 0; u < 16; u++) {
                int k = k0 + bkh + u;
                float v;
                if (k < K) {
                    size_t gi = b_mode
                        ? (size_t)bhead * (512 * 64) + (size_t)k * 64 + bf
                        : (size_t)k * 512 + n0 + bc;
                    v = Bsrc[gi];
                } else v = 0.f;
                split1(v, hb[u], lb[u]);
            }
            const int lb0 = bc * LDK + bkh;
#pragma unroll
            for (int u = 0; u < 4; u++) {
                *(uint2*)&Bh[lb0 + 4*u] = make_uint2(pack2(hb[4*u],hb[4*u+1]), pack2(hb[4*u+2],hb[4*u+3]));
                *(uint2*)&Bl[lb0 + 4*u] = make_uint2(pack2(lb[4*u],lb[4*u+1]), pack2(lb[4*u+2],lb[4*u+3]));
            }
        }
        __syncthreads();

        bf16x8 ah[4], al[4], bh[4], bl[4];
#pragma unroll
        for (int s = 0; s < 4; s++) {
            ah[s] = *(const bf16x8*)&Ah[afrag0 + s * 16 * LDK];
            al[s] = *(const bf16x8*)&Al[afrag0 + s * 16 * LDK];
        }
#pragma unroll
        for (int t = 0; t < 4; t++) {
            bh[t] = *(const bf16x8*)&Bh[bfrag0 + t * 16 * LDK];
            bl[t] = *(const bf16x8*)&Bl[bfrag0 + t * 16 * LDK];
        }
#pragma unroll
        for (int s = 0; s < 4; s++)
#pragma unroll
            for (int t = 0; t < 4; t++) {
                acc[s][t] = __builtin_amdgcn_mfma_f32_16x16x32_bf16(ah[s], bh[t], acc[s][t], 0, 0, 0);
                acc[s][t] = __builtin_amdgcn_mfma_f32_16x16x32_bf16(ah[s], bl[t], acc[s][t], 0, 0, 0);
                acc[s][t] = __builtin_amdgcn_mfma_f32_16x16x32_bf16(al[s], bh[t], acc[s][t], 0, 0, 0);
            }
    }

    if (b_mode == 0) {
        // fp32 x epilogue (C/D: col=lane&15, row=(lane>>4)*4+reg)
#pragma unroll
        for (int s = 0; s < 4; s++) {
            const int gr0 = m0 + rw * 64 + s * 16 + (lane >> 4) * 4;
#pragma unroll
            for (int r = 0; r < 4; r++) {
                const unsigned grow = gr0 + r;
                const unsigned b = grow / (unsigned)rpb;
                const unsigned rr = grow - b * rpb;
                float* crow = C + ((size_t)b * NN + noff + rr) * HIDD;
#pragma unroll
                for (int t = 0; t < 4; t++) {
                    crow[n0 + cw * 64 + t * 16 + (lane & 15)] = acc[s][t][r];
                }
            }
        }
    } else {
        // Ht fragment-layout split-bf16 epilogue
        const int hd = (n0 + cw * 64) >> 6;
        const int fq = lane & 15;
#pragma unroll
        for (int s = 0; s < 4; s++) {
            const int m_s = m0 + rw * 64 + s * 16 + (lane >> 4) * 4;  // rows m_s..m_s+3
            const unsigned b = (unsigned)m_s / 320u;   // constant over r (m_s%4==0)
            const int jb = m_s - b * 320;              // node j base, mult of 4
            const int ks = jb >> 5;
            const int jg2 = (jb >> 3) & 3;
            const int eb = jb & 7;                     // 0 or 4
            const size_t slab = (size_t)b * 8 + hd;
#pragma unroll
            for (int t = 0; t < 4; t++) {
                unsigned short h0,h1,h2,h3,l0,l1,l2,l3;
                split1(acc[s][t][0],h0,l0); split1(acc[s][t][1],h1,l1);
                split1(acc[s][t][2],h2,l2); split1(acc[s][t][3],h3,l3);
                const size_t base = (((slab * 10 + ks) * 4 + t) * 512
                                     + (size_t)(fq | (jg2 << 4)) * 8) + eb;
                *(uint2*)&Hthi[base] = make_uint2(pack2(h0,h1), pack2(h2,h3));
                *(uint2*)&Htlo[base] = make_uint2(pack2(l0,l1), pack2(l2,l3));
            }
        }
    }
}

// ---------------------------------------------------------------------------
// MFMA GAT attention, one block per (b, head) — 512 blocks, all co-resident.
// v2 restructure: register-resident A-fragments.
//   Thread (w, jg=lane>>4, fq=lane&15) computes scores for row i=ip*64+w*16+fq,
//   j = ks*32+jg*8+e  — exactly the A-frag element layout of its own lane, so
//   P never touches LDS and the main loop has ZERO barriers / ZERO atomics.
//   Wave w owns i-tiles mt=ip*4+w (acc[5][4] over all 4 f-tiles).
// Pre-pass: fi/fj via 15-shfl value-splitting reduction into per-wave LDS
//   slots (no atomics), combined once. l accumulated in registers, reduced
//   with 2 shfl_xor at the end.
// ---------------------------------------------------------------------------
__global__ __launch_bounds__(256) void attn_mfma(
    const unsigned short* __restrict__ Hthi, const unsigned short* __restrict__ Htlo,
    const float* __restrict__ asrc, const float* __restrict__ adst,
    const int*   __restrict__ adj,  const float* __restrict__ elog,
    float* __restrict__ xout, int apply_elu)
{
    __shared__ float ff4[2][4][NN];   // per-wave fi(0)/fj(1) partials, 10 KB
    __shared__ float fjs[NN];
    __shared__ float ls[NN];

    const int bh = blockIdx.x;          // b*8 + hd
    const int hd = bh & 7, b = bh >> 3;
    const int tid = threadIdx.x, lane = tid & 63, w = tid >> 6;
    const int fq = lane & 15, jg = lane >> 4;

    // ---- pre-pass: fi/fj partials over f in [w*16, w*16+16) ----
    {
        const int f = (w << 4) + fq;
        const float as = asrc[hd * 64 + f];
        const float ad = adst[hd * 64 + f];
#pragma unroll 2
        for (int ks = 0; ks < 10; ks++) {
            const size_t off = (((size_t)bh * 10 + ks) * 4 + w) * 512 + (size_t)lane * 8;
            bf16x8 hh = *(const bf16x8*)&Hthi[off];
            bf16x8 hl = *(const bf16x8*)&Htlo[off];
            float v[16];
#pragma unroll
            for (int e = 0; e < 8; e++) {
                float hv = __uint_as_float(((unsigned)(unsigned short)hh[e]) << 16)
                         + __uint_as_float(((unsigned)(unsigned short)hl[e]) << 16);
                v[e] = hv * as; v[8 + e] = hv * ad;
            }
            // value-splitting reduce over the 16-lane fq group:
            // after step d, values-per-lane halve; lane fq ends with total of
            // original v[fq]  (fq<8: fi[e=fq], fq>=8: fj[e=fq-8])
#pragma unroll
            for (int d = 8; d >= 1; d >>= 1) {
                const bool up = (fq & d) != 0;
#pragma unroll
                for (int m = 0; m < d; m++) {
                    float snd = up ? v[m] : v[m + d];
                    float rec = __shfl_xor(snd, d);
                    v[m] = (up ? v[m + d] : v[m]) + rec;
                }
            }
            ff4[fq >> 3][w][ks * 32 + jg * 8 + (fq & 7)] = v[0];
        }
    }
    __syncthreads();

    // combine 4-wave partials: fi -> registers (5 per thread), fj -> LDS
    float fir[5];
#pragma unroll
    for (int ip = 0; ip < 5; ip++) {
        const int i = ip * 64 + (w << 4) + fq;
        fir[ip] = (ff4[0][0][i] + ff4[0][1][i]) + (ff4[0][2][i] + ff4[0][3][i]);
    }
    for (int r = tid; r < NN; r += 256)
        fjs[r] = (ff4[1][0][r] + ff4[1][1][r]) + (ff4[1][2][r] + ff4[1][3][r]);
    __syncthreads();

    floatx4 acc[5][4];
#pragma unroll
    for (int ip = 0; ip < 5; ip++)
#pragma unroll
        for (int nt = 0; nt < 4; nt++) acc[ip][nt] = (floatx4)0.f;
    float lacc[5] = {0.f, 0.f, 0.f, 0.f, 0.f};

    for (int ks = 0; ks < 10; ks++) {
        // B-frags straight from global (already fragment layout), all 4 f-tiles
        bf16x8 bhf[4], blf[4];
#pragma unroll
        for (int nt = 0; nt < 4; nt++) {
            const size_t off = (((size_t)bh * 10 + ks) * 4 + nt) * 512 + (size_t)lane * 8;
            bhf[nt] = *(const bf16x8*)&Hthi[off];
            blf[nt] = *(const bf16x8*)&Htlo[off];
        }
        const int j8 = ks * 32 + jg * 8;
        const float4 fj0 = *(const float4*)&fjs[j8];
        const float4 fj1 = *(const float4*)&fjs[j8 + 4];

#pragma unroll
        for (int ip = 0; ip < 5; ip++) {
            const int i = ip * 64 + (w << 4) + fq;
            const float fiv = fir[ip];
            const size_t g = (size_t)i * NN + j8;
            const int4   a0 = *(const int4*)&adj[g];
            const int4   a1 = *(const int4*)&adj[g + 4];
            const float4 e0 = *(const float4*)&elog[g];
            const float4 e1 = *(const float4*)&elog[g + 4];
            float p[8];
            {
                float s;
                s = fiv + fj0.x; s = fmaxf(s, 0.2f*s); s = a0.x ? (s + e0.x) : -INFINITY; p[0] = __expf(s);
                s = fiv + fj0.y; s = fmaxf(s, 0.2f*s); s = a0.y ? (s + e0.y) : -INFINITY; p[1] = __expf(s);
                s = fiv + fj0.z; s = fmaxf(s, 0.2f*s); s = a0.z ? (s + e0.z) : -INFINITY; p[2] = __expf(s);
                s = fiv + fj0.w; s = fmaxf(s, 0.2f*s); s = a0.w ? (s + e0.w) : -INFINITY; p[3] = __expf(s);
                s = fiv + fj1.x; s = fmaxf(s, 0.2f*s); s = a1.x ? (s + e1.x) : -INFINITY; p[4] = __expf(s);
                s = fiv + fj1.y; s = fmaxf(s, 0.2f*s); s = a1.y ? (s + e1.y) : -INFINITY; p[5] = __expf(s);
                s = fiv + fj1.z; s = fmaxf(s, 0.2f*s); s = a1.z ? (s + e1.z) : -INFINITY; p[6] = __expf(s);
                s = fiv + fj1.w; s = fmaxf(s, 0.2f*s); s = a1.w ? (s + e1.w) : -INFINITY; p[7] = __expf(s);
            }
            lacc[ip] += ((p[0]+p[1]) + (p[2]+p[3])) + ((p[4]+p[5]) + (p[6]+p[7]));

            unsigned short ph[8], pl[8];
#pragma unroll
            for (int e = 0; e < 8; e++) split1(p[e], ph[e], pl[e]);
            union { uint4 u; bf16x8 v; } ua, ul;
            ua.u = make_uint4(pack2(ph[0],ph[1]), pack2(ph[2],ph[3]),
                              pack2(ph[4],ph[5]), pack2(ph[6],ph[7]));
            ul.u = make_uint4(pack2(pl[0],pl[1]), pack2(pl[2],pl[3]),
                              pack2(pl[4],pl[5]), pack2(pl[6],pl[7]));
            const bf16x8 ah = ua.v, al = ul.v;
#pragma unroll
            for (int nt = 0; nt < 4; nt++) {
                acc[ip][nt] = __builtin_amdgcn_mfma_f32_16x16x32_bf16(ah, bhf[nt], acc[ip][nt], 0, 0, 0);
                acc[ip][nt] = __builtin_amdgcn_mfma_f32_16x16x32_bf16(ah, blf[nt], acc[ip][nt], 0, 0, 0);
                acc[ip][nt] = __builtin_amdgcn_mfma_f32_16x16x32_bf16(al, bhf[nt], acc[ip][nt], 0, 0, 0);
            }
        }
    }

    // ---- l reduction: sum over the 4 jg lanes holding the same i ----
#pragma unroll
    for (int ip = 0; ip < 5; ip++) {
        float l = lacc[ip];
        l += __shfl_xor(l, 16);
        l += __shfl_xor(l, 32);
        if (jg == 0) ls[ip * 64 + (w << 4) + fq] = l;
    }
    __syncthreads();

    // ---- epilogue: D col(f)=lane&15, row(i)=(lane>>4)*4+reg ----
#pragma unroll
    for (int ip = 0; ip < 5; ip++) {
        const int ib = (ip * 4 + w) * 16 + jg * 4;
#pragma unroll
        for (int r = 0; r < 4; r++) {
            const float lv = ls[ib + r];
            const float inv = (lv > 0.f) ? 1.f / lv : 0.f;   // fully-masked row -> 0
            float* orow = xout + ((size_t)(b * NN + ib + r)) * HIDD + hd * 64;
#pragma unroll
            for (int nt = 0; nt < 4; nt++) {
                float vv = acc[ip][nt][r] * inv;
                if (apply_elu) vv = (vv > 0.f) ? vv : __expf(vv) - 1.f;
                orow[nt * 16 + fq] = vv;
            }
        }
    }
}

// ---------------------------------------------------------------------------
// Workspace: Ht hi plane 20,971,520 B + lo plane 20,971,520 B
//          = 41,943,040 B == out bytes exactly. Nothing else in ws.
// Flow: proj -> d_out (x); per layer: gemm_h reads x, writes Ht(ws);
//       attn reads Ht(ws), writes x'/final to d_out. Strictly sequential.
// ---------------------------------------------------------------------------
extern "C" void kernel_launch(void* const* d_in, const int* in_sizes, int n_in,
                              void* d_out, int out_size, void* d_ws, size_t ws_size,
                              hipStream_t stream)
{
    (void)in_sizes; (void)n_in; (void)out_size; (void)ws_size;
    const float* text     = (const float*)d_in[0];
    const float* visual   = (const float*)d_in[1];
    const float* acoustic = (const float*)d_in[2];
    const int*   adj      = (const int*)d_in[3];
    const float* Wt       = (const float*)d_in[4];
    const float* Wv       = (const float*)d_in[5];
    const float* Wa       = (const float*)d_in[6];
    const float* Wg       = (const float*)d_in[7];
    const float* a_src    = (const float*)d_in[8];
    const float* a_dst    = (const float*)d_in[9];
    const float* elog     = (const float*)d_in[10];

    float* xbuf = (float*)d_out;
    unsigned short* Hthi = (unsigned short*)d_ws;
    unsigned short* Htlo = Hthi + (size_t)512 * 10 * 4 * 512;   // 10,485,760 shorts

    gemm_mfma<<<dim3((BB*NT)/128, 4), 256, 0, stream>>>(text,     Wt, xbuf, nullptr, nullptr, BB*NT, 768, 0, NT, 0);
    gemm_mfma<<<dim3((BB*NV)/128, 4), 256, 0, stream>>>(visual,   Wv, xbuf, nullptr, nullptr, BB*NV,  47, 0, NV, NT);
    gemm_mfma<<<dim3((BB*NA)/128, 4), 256, 0, stream>>>(acoustic, Wa, xbuf, nullptr, nullptr, BB*NA,  74, 0, NA, NT + NV);

    for (int l = 0; l < 2; l++) {
        const float* Wg_l = Wg + (size_t)l * NHEAD * HIDD * FD;
        gemm_mfma<<<dim3((BB*NN)/128, 4), 256, 0, stream>>>(xbuf, Wg_l, nullptr, Hthi, Htlo, BB*NN, HIDD, 1, NN, 0);
        attn_mfma<<<BB * NHEAD, 256, 0, stream>>>(
            Hthi, Htlo, a_src + l * NHEAD * FD, a_dst + l * NHEAD * FD,
            adj, elog, xbuf, (l == 0) ? 1 : 0);
    }
}

// Round 2
// 416.841 us; speedup vs baseline: 1.1482x; 1.1482x over previous
//
#include <hip/hip_runtime.h>
#include <hip/hip_bf16.h>
#include <math.h>

#define BB 64
#define NN 320
#define NT 256
#define NV 32
#define NA 32
#define HIDD 512
#define NHEAD 8
#define FD 64

#define LDK 40    // GEMM LDS k-stride (bf16 units)

typedef __attribute__((ext_vector_type(8))) short bf16x8;
typedef __attribute__((ext_vector_type(4))) float floatx4;

__device__ __forceinline__ void split1(float v, unsigned short& h, unsigned short& l) {
    unsigned u = __float_as_uint(v);
    unsigned hu = u & 0xFFFF0000u;
    float lf = v - __uint_as_float(hu);
    h = (unsigned short)(hu >> 16);
    l = (unsigned short)(__float_as_uint(lf) >> 16);
}
__device__ __forceinline__ unsigned pack2(unsigned short a, unsigned short b) {
    return (unsigned)a | ((unsigned)b << 16);
}

// ---------------------------------------------------------------------------
// Split-bf16 MFMA GEMM. C[M,512] = A[M,K] @ B[K,512], 3-pass hi/lo.
// 128x128 tile, BK=32, 4 waves each 64x64.
// b_mode 0 (projections): epilogue writes fp32 x with batch/node remap.
// b_mode 1 (gemm_h): B = Wg_l [head][d][f]; epilogue writes Ht split-bf16
//   hi/lo DIRECTLY in MFMA B-fragment layout:
//   Ht[slab=b*8+hd][ks=j>>5][nt=f>>4][lane=(f&15)|(((j>>3)&3)<<4)][e=j&7]
//   (so attn loads B-frags as contiguous 16B per lane). No fp32 C written.
// ---------------------------------------------------------------------------
__global__ __launch_bounds__(256) void gemm_mfma(
    const float* __restrict__ A, const float* __restrict__ Bsrc,
    float* __restrict__ C, unsigned short* __restrict__ Hthi,
    unsigned short* __restrict__ Htlo, int M, int K, int b_mode, int rpb, int noff)
{
    __shared__ unsigned short Ah[128 * LDK];
    __shared__ unsigned short Al[128 * LDK];
    __shared__ unsigned short Bh[128 * LDK];
    __shared__ unsigned short Bl[128 * LDK];

    const int tid  = threadIdx.x;
    const int lane = tid & 63;
    const int w    = tid >> 6;
    const int rw   = w >> 1, cw = w & 1;
    const int m0   = blockIdx.x * 128;
    const int n0   = blockIdx.y * 128;

    floatx4 acc[4][4];
#pragma unroll
    for (int s = 0; s < 4; s++)
#pragma unroll
        for (int t = 0; t < 4; t++) acc[s][t] = (floatx4)0.f;

    const int arow = tid >> 1;
    const int akh  = (tid & 1) * 16;
    const int bc   = tid & 127;
    const int bkh  = (tid >> 7) * 16;
    const int bhead = (n0 + bc) >> 6;
    const int bf    = (n0 + bc) & 63;

    const int afrag0 = (rw * 64 + (lane & 15)) * LDK + (lane >> 4) * 8;
    const int bfrag0 = (cw * 64 + (lane & 15)) * LDK + (lane >> 4) * 8;

    for (int k0 = 0; k0 < K; k0 += 32) {
        __syncthreads();
        {
            const float* ga = A + (size_t)(m0 + arow) * K + k0 + akh;
            const int la = arow * LDK + akh;
            if (k0 + 32 <= K) {
#pragma unroll
                for (int u = 0; u < 4; u++) {
                    float4 v = *(const float4*)(ga + 4 * u);
                    unsigned short h0,h1,h2,h3,l0,l1,l2,l3;
                    split1(v.x,h0,l0); split1(v.y,h1,l1);
                    split1(v.z,h2,l2); split1(v.w,h3,l3);
                    *(uint2*)&Ah[la + 4*u] = make_uint2(pack2(h0,h1), pack2(h2,h3));
                    *(uint2*)&Al[la + 4*u] = make_uint2(pack2(l0,l1), pack2(l2,l3));
                }
            } else {
#pragma unroll
                for (int u = 0; u < 16; u++) {
                    float v = (k0 + akh + u < K) ? ga[u] : 0.f;
                    unsigned short h, l; split1(v, h, l);
                    Ah[la + u] = h; Al[la + u] = l;
                }
            }
        }
        {
            unsigned short hb[16], lb[16];
#pragma unroll
            for (int u = 0; u < 16; u++) {
                int k = k0 + bkh + u;
                float v;
                if (k < K) {
                    size_t gi = b_mode
                        ? (size_t)bhead * (512 * 64) + (size_t)k * 64 + bf
                        : (size_t)k * 512 + n0 + bc;
                    v = Bsrc[gi];
                } else v = 0.f;
                split1(v, hb[u], lb[u]);
            }
            const int lb0 = bc * LDK + bkh;
#pragma unroll
            for (int u = 0; u < 4; u++) {
                *(uint2*)&Bh[lb0 + 4*u] = make_uint2(pack2(hb[4*u],hb[4*u+1]), pack2(hb[4*u+2],hb[4*u+3]));
                *(uint2*)&Bl[lb0 + 4*u] = make_uint2(pack2(lb[4*u],lb[4*u+1]), pack2(lb[4*u+2],lb[4*u+3]));
            }
        }
        __syncthreads();

        bf16x8 ah[4], al[4], bh[4], bl[4];
#pragma unroll
        for (int s = 0; s < 4; s++) {
            ah[s] = *(const bf16x8*)&Ah[afrag0 + s * 16 * LDK];
            al[s] = *(const bf16x8*)&Al[afrag0 + s * 16 * LDK];
        }
#pragma unroll
        for (int t = 0; t < 4; t++) {
            bh[t] = *(const bf16x8*)&Bh[bfrag0 + t * 16 * LDK];
            bl[t] = *(const bf16x8*)&Bl[bfrag0 + t * 16 * LDK];
        }
#pragma unroll
        for (int s = 0; s < 4; s++)
#pragma unroll
            for (int t = 0; t < 4; t++) {
                acc[s][t] = __builtin_amdgcn_mfma_f32_16x16x32_bf16(ah[s], bh[t], acc[s][t], 0, 0, 0);
                acc[s][t] = __builtin_amdgcn_mfma_f32_16x16x32_bf16(ah[s], bl[t], acc[s][t], 0, 0, 0);
                acc[s][t] = __builtin_amdgcn_mfma_f32_16x16x32_bf16(al[s], bh[t], acc[s][t], 0, 0, 0);
            }
    }

    if (b_mode == 0) {
        // fp32 x epilogue (C/D: col=lane&15, row=(lane>>4)*4+reg)
#pragma unroll
        for (int s = 0; s < 4; s++) {
            const int gr0 = m0 + rw * 64 + s * 16 + (lane >> 4) * 4;
#pragma unroll
            for (int r = 0; r < 4; r++) {
                const unsigned grow = gr0 + r;
                const unsigned b = grow / (unsigned)rpb;
                const unsigned rr = grow - b * rpb;
                float* crow = C + ((size_t)b * NN + noff + rr) * HIDD;
#pragma unroll
                for (int t = 0; t < 4; t++) {
                    crow[n0 + cw * 64 + t * 16 + (lane & 15)] = acc[s][t][r];
                }
            }
        }
    } else {
        // Ht fragment-layout split-bf16 epilogue
        const int hd = (n0 + cw * 64) >> 6;
        const int fq = lane & 15;
#pragma unroll
        for (int s = 0; s < 4; s++) {
            const int m_s = m0 + rw * 64 + s * 16 + (lane >> 4) * 4;  // rows m_s..m_s+3
            const unsigned b = (unsigned)m_s / 320u;   // constant over r (m_s%4==0)
            const int jb = m_s - b * 320;              // node j base, mult of 4
            const int ks = jb >> 5;
            const int jg2 = (jb >> 3) & 3;
            const int eb = jb & 7;                     // 0 or 4
            const size_t slab = (size_t)b * 8 + hd;
#pragma unroll
            for (int t = 0; t < 4; t++) {
                unsigned short h0,h1,h2,h3,l0,l1,l2,l3;
                split1(acc[s][t][0],h0,l0); split1(acc[s][t][1],h1,l1);
                split1(acc[s][t][2],h2,l2); split1(acc[s][t][3],h3,l3);
                const size_t base = (((slab * 10 + ks) * 4 + t) * 512
                                     + (size_t)(fq | (jg2 << 4)) * 8) + eb;
                *(uint2*)&Hthi[base] = make_uint2(pack2(h0,h1), pack2(h2,h3));
                *(uint2*)&Htlo[base] = make_uint2(pack2(l0,l1), pack2(l2,l3));
            }
        }
    }
}

// ---------------------------------------------------------------------------
// MFMA GAT attention, one block per (b, head) — 512 blocks, 2/CU.
// v3: register-resident A-fragments (v2 dataflow) + occupancy fix.
//   __launch_bounds__(256,2) pins total regs <= 256/wave (v2 spilled past the
//   1-wave/SIMD cliff: Occupancy 20.6 -> 11.1).
//   Per ks the body is two phases: (1) score/exp/split for all 5 ip-groups
//   into ahh[5]/all[5] (40 VGPR), (2) 60 MFMAs with all operands resident
//   (acc 80 + A 40 + B 32 ~= 200 total). Zero barriers/atomics in main loop.
// ---------------------------------------------------------------------------
__global__ __launch_bounds__(256, 2) void attn_mfma(
    const unsigned short* __restrict__ Hthi, const unsigned short* __restrict__ Htlo,
    const float* __restrict__ asrc, const float* __restrict__ adst,
    const int*   __restrict__ adj,  const float* __restrict__ elog,
    float* __restrict__ xout, int apply_elu)
{
    __shared__ float ff4[2][4][NN];   // per-wave fi(0)/fj(1) partials, 10 KB
    __shared__ float fjs[NN];
    __shared__ float ls[NN];

    const int bh = blockIdx.x;          // b*8 + hd
    const int hd = bh & 7, b = bh >> 3;
    const int tid = threadIdx.x, lane = tid & 63, w = tid >> 6;
    const int fq = lane & 15, jg = lane >> 4;

    // ---- pre-pass: fi/fj partials over f in [w*16, w*16+16) ----
    {
        const int f = (w << 4) + fq;
        const float as = asrc[hd * 64 + f];
        const float ad = adst[hd * 64 + f];
#pragma unroll 2
        for (int ks = 0; ks < 10; ks++) {
            const unsigned off = (((unsigned)bh * 10 + ks) * 4 + w) * 512 + (unsigned)lane * 8;
            bf16x8 hh = *(const bf16x8*)&Hthi[off];
            bf16x8 hl = *(const bf16x8*)&Htlo[off];
            float v[16];
#pragma unroll
            for (int e = 0; e < 8; e++) {
                float hv = __uint_as_float(((unsigned)(unsigned short)hh[e]) << 16)
                         + __uint_as_float(((unsigned)(unsigned short)hl[e]) << 16);
                v[e] = hv * as; v[8 + e] = hv * ad;
            }
            // value-splitting reduce over the 16-lane fq group:
            // after step d, values-per-lane halve; lane fq ends with total of
            // original v[fq]  (fq<8: fi[e=fq], fq>=8: fj[e=fq-8])
#pragma unroll
            for (int d = 8; d >= 1; d >>= 1) {
                const bool up = (fq & d) != 0;
#pragma unroll
                for (int m = 0; m < d; m++) {
                    float snd = up ? v[m] : v[m + d];
                    float rec = __shfl_xor(snd, d);
                    v[m] = (up ? v[m + d] : v[m]) + rec;
                }
            }
            ff4[fq >> 3][w][ks * 32 + jg * 8 + (fq & 7)] = v[0];
        }
    }
    __syncthreads();

    // combine 4-wave partials: fi -> registers (5 per thread), fj -> LDS
    float fir[5];
#pragma unroll
    for (int ip = 0; ip < 5; ip++) {
        const int i = ip * 64 + (w << 4) + fq;
        fir[ip] = (ff4[0][0][i] + ff4[0][1][i]) + (ff4[0][2][i] + ff4[0][3][i]);
    }
    for (int r = tid; r < NN; r += 256)
        fjs[r] = (ff4[1][0][r] + ff4[1][1][r]) + (ff4[1][2][r] + ff4[1][3][r]);
    __syncthreads();

    floatx4 acc[5][4];
#pragma unroll
    for (int ip = 0; ip < 5; ip++)
#pragma unroll
        for (int nt = 0; nt < 4; nt++) acc[ip][nt] = (floatx4)0.f;
    float lacc[5] = {0.f, 0.f, 0.f, 0.f, 0.f};

    for (int ks = 0; ks < 10; ks++) {
        // B-frags straight from global (already fragment layout), all 4 f-tiles
        bf16x8 bhf[4], blf[4];
#pragma unroll
        for (int nt = 0; nt < 4; nt++) {
            const unsigned off = (((unsigned)bh * 10 + ks) * 4 + nt) * 512 + (unsigned)lane * 8;
            bhf[nt] = *(const bf16x8*)&Hthi[off];
            blf[nt] = *(const bf16x8*)&Htlo[off];
        }
        const int j8 = ks * 32 + jg * 8;
        const float4 fj0 = *(const float4*)&fjs[j8];
        const float4 fj1 = *(const float4*)&fjs[j8 + 4];

        // ---- phase 1: scores -> exp -> split-bf16 A-frags for all 5 ip ----
        bf16x8 ahh[5], all[5];
#pragma unroll
        for (int ip = 0; ip < 5; ip++) {
            const int i = ip * 64 + (w << 4) + fq;
            const float fiv = fir[ip];
            const unsigned g = (unsigned)i * NN + j8;
            const int4   a0 = *(const int4*)&adj[g];
            const int4   a1 = *(const int4*)&adj[g + 4];
            const float4 e0 = *(const float4*)&elog[g];
            const float4 e1 = *(const float4*)&elog[g + 4];
            float p[8];
            {
                float s;
                s = fiv + fj0.x; s = fmaxf(s, 0.2f*s); s = a0.x ? (s + e0.x) : -INFINITY; p[0] = __expf(s);
                s = fiv + fj0.y; s = fmaxf(s, 0.2f*s); s = a0.y ? (s + e0.y) : -INFINITY; p[1] = __expf(s);
                s = fiv + fj0.z; s = fmaxf(s, 0.2f*s); s = a0.z ? (s + e0.z) : -INFINITY; p[2] = __expf(s);
                s = fiv + fj0.w; s = fmaxf(s, 0.2f*s); s = a0.w ? (s + e0.w) : -INFINITY; p[3] = __expf(s);
                s = fiv + fj1.x; s = fmaxf(s, 0.2f*s); s = a1.x ? (s + e1.x) : -INFINITY; p[4] = __expf(s);
                s = fiv + fj1.y; s = fmaxf(s, 0.2f*s); s = a1.y ? (s + e1.y) : -INFINITY; p[5] = __expf(s);
                s = fiv + fj1.z; s = fmaxf(s, 0.2f*s); s = a1.z ? (s + e1.z) : -INFINITY; p[6] = __expf(s);
                s = fiv + fj1.w; s = fmaxf(s, 0.2f*s); s = a1.w ? (s + e1.w) : -INFINITY; p[7] = __expf(s);
            }
            lacc[ip] += ((p[0]+p[1]) + (p[2]+p[3])) + ((p[4]+p[5]) + (p[6]+p[7]));

            unsigned short ph[8], pl[8];
#pragma unroll
            for (int e = 0; e < 8; e++) split1(p[e], ph[e], pl[e]);
            union { uint4 u; bf16x8 v; } ua, ul;
            ua.u = make_uint4(pack2(ph[0],ph[1]), pack2(ph[2],ph[3]),
                              pack2(ph[4],ph[5]), pack2(ph[6],ph[7]));
            ul.u = make_uint4(pack2(pl[0],pl[1]), pack2(pl[2],pl[3]),
                              pack2(pl[4],pl[5]), pack2(pl[6],pl[7]));
            ahh[ip] = ua.v; all[ip] = ul.v;
        }

        // ---- phase 2: 60 MFMAs, 20 independent 3-chains, operands resident --
#pragma unroll
        for (int ip = 0; ip < 5; ip++)
#pragma unroll
            for (int nt = 0; nt < 4; nt++) {
                acc[ip][nt] = __builtin_amdgcn_mfma_f32_16x16x32_bf16(ahh[ip], bhf[nt], acc[ip][nt], 0, 0, 0);
                acc[ip][nt] = __builtin_amdgcn_mfma_f32_16x16x32_bf16(ahh[ip], blf[nt], acc[ip][nt], 0, 0, 0);
                acc[ip][nt] = __builtin_amdgcn_mfma_f32_16x16x32_bf16(all[ip], bhf[nt], acc[ip][nt], 0, 0, 0);
            }
    }

    // ---- l reduction: sum over the 4 jg lanes holding the same i ----
#pragma unroll
    for (int ip = 0; ip < 5; ip++) {
        float l = lacc[ip];
        l += __shfl_xor(l, 16);
        l += __shfl_xor(l, 32);
        if (jg == 0) ls[ip * 64 + (w << 4) + fq] = l;
    }
    __syncthreads();

    // ---- epilogue: D col(f)=lane&15, row(i)=(lane>>4)*4+reg ----
#pragma unroll
    for (int ip = 0; ip < 5; ip++) {
        const int ib = (ip * 4 + w) * 16 + jg * 4;
#pragma unroll
        for (int r = 0; r < 4; r++) {
            const float lv = ls[ib + r];
            const float inv = (lv > 0.f) ? 1.f / lv : 0.f;   // fully-masked row -> 0
            float* orow = xout + ((size_t)(b * NN + ib + r)) * HIDD + hd * 64;
#pragma unroll
            for (int nt = 0; nt < 4; nt++) {
                float vv = acc[ip][nt][r] * inv;
                if (apply_elu) vv = (vv > 0.f) ? vv : __expf(vv) - 1.f;
                orow[nt * 16 + fq] = vv;
            }
        }
    }
}

// ---------------------------------------------------------------------------
// Workspace: Ht hi plane 20,971,520 B + lo plane 20,971,520 B
//          = 41,943,040 B == out bytes exactly. Nothing else in ws.
// Flow: proj -> d_out (x); per layer: gemm_h reads x, writes Ht(ws);
//       attn reads Ht(ws), writes x'/final to d_out. Strictly sequential.
// ---------------------------------------------------------------------------
extern "C" void kernel_launch(void* const* d_in, const int* in_sizes, int n_in,
                              void* d_out, int out_size, void* d_ws, size_t ws_size,
                              hipStream_t stream)
{
    (void)in_sizes; (void)n_in; (void)out_size; (void)ws_size;
    const float* text     = (const float*)d_in[0];
    const float* visual   = (const float*)d_in[1];
    const float* acoustic = (const float*)d_in[2];
    const int*   adj      = (const int*)d_in[3];
    const float* Wt       = (const float*)d_in[4];
    const float* Wv       = (const float*)d_in[5];
    const float* Wa       = (const float*)d_in[6];
    const float* Wg       = (const float*)d_in[7];
    const float* a_src    = (const float*)d_in[8];
    const float* a_dst    = (const float*)d_in[9];
    const float* elog     = (const float*)d_in[10];

    float* xbuf = (float*)d_out;
    unsigned short* Hthi = (unsigned short*)d_ws;
    unsigned short* Htlo = Hthi + (size_t)512 * 10 * 4 * 512;   // 10,485,760 shorts

    gemm_mfma<<<dim3((BB*NT)/128, 4), 256, 0, stream>>>(text,     Wt, xbuf, nullptr, nullptr, BB*NT, 768, 0, NT, 0);
    gemm_mfma<<<dim3((BB*NV)/128, 4), 256, 0, stream>>>(visual,   Wv, xbuf, nullptr, nullptr, BB*NV,  47, 0, NV, NT);
    gemm_mfma<<<dim3((BB*NA)/128, 4), 256, 0, stream>>>(acoustic, Wa, xbuf, nullptr, nullptr, BB*NA,  74, 0, NA, NT + NV);

    for (int l = 0; l < 2; l++) {
        const float* Wg_l = Wg + (size_t)l * NHEAD * HIDD * FD;
        gemm_mfma<<<dim3((BB*NN)/128, 4), 256, 0, stream>>>(xbuf, Wg_l, nullptr, Hthi, Htlo, BB*NN, HIDD, 1, NN, 0);
        attn_mfma<<<BB * NHEAD, 256, 0, stream>>>(
            Hthi, Htlo, a_src + l * NHEAD * FD, a_dst + l * NHEAD * FD,
            adj, elog, xbuf, (l == 0) ? 1 : 0);
    }
}

// Round 3
// 372.139 us; speedup vs baseline: 1.2861x; 1.1201x over previous
//
#include <hip/hip_runtime.h>
#include <hip/hip_bf16.h>
#include <math.h>

#define BB 64
#define NN 320
#define NT 256
#define NV 32
#define NA 32
#define HIDD 512
#define NHEAD 8
#define FD 64

#define LDK 40    // GEMM LDS k-stride (bf16 units)

typedef __attribute__((ext_vector_type(8))) short bf16x8;
typedef __attribute__((ext_vector_type(4))) float floatx4;

// device-global scratch (layer-overwritten, stream-ordered):
__device__ float me_g[NN * NN];        // adj-masked exp(edge_logits), built once
__device__ float fif_g[512 * NN];      // fi[b*8+hd][node], written by gemm_h
__device__ float fjf_g[512 * NN];      // fj[b*8+hd][node]

__device__ __forceinline__ void split1(float v, unsigned short& h, unsigned short& l) {
    unsigned u = __float_as_uint(v);
    unsigned hu = u & 0xFFFF0000u;
    float lf = v - __uint_as_float(hu);
    h = (unsigned short)(hu >> 16);
    l = (unsigned short)(__float_as_uint(lf) >> 16);
}
__device__ __forceinline__ unsigned pack2(unsigned short a, unsigned short b) {
    return (unsigned)a | ((unsigned)b << 16);
}

// ---------------------------------------------------------------------------
// me = adj ? exp(elog) : 0   (102400 elems, float4 per thread)
// ---------------------------------------------------------------------------
__global__ __launch_bounds__(256) void build_me(
    const int* __restrict__ adj, const float* __restrict__ elog)
{
    const int i4 = (blockIdx.x * 256 + threadIdx.x) * 4;
    const int4   a = *(const int4*)&adj[i4];
    const float4 e = *(const float4*)&elog[i4];
    float4 m;
    m.x = a.x ? __expf(e.x) : 0.f;
    m.y = a.y ? __expf(e.y) : 0.f;
    m.z = a.z ? __expf(e.z) : 0.f;
    m.w = a.w ? __expf(e.w) : 0.f;
    *(float4*)&me_g[i4] = m;
}

// ---------------------------------------------------------------------------
// Split-bf16 MFMA GEMM. C[M,512] = A[M,K] @ B[K,512], 3-pass hi/lo.
// 128x128 tile, BK=32, 4 waves each 64x64.
// b_mode 0 (projections): epilogue writes fp32 x with batch/node remap.
// b_mode 1 (gemm_h): B = Wg_l [head][d][f]; epilogue writes Ht split-bf16
//   in MFMA B-fragment layout AND folds fi/fj = H.a_src / H.a_dst per
//   (row, head) via 4-step shfl reduce over the 16 fq lanes (exact fp32,
//   no atomics: each (row,head) lives in exactly one block/wave).
// ---------------------------------------------------------------------------
__global__ __launch_bounds__(256) void gemm_mfma(
    const float* __restrict__ A, const float* __restrict__ Bsrc,
    float* __restrict__ C, unsigned short* __restrict__ Hthi,
    unsigned short* __restrict__ Htlo, const float* __restrict__ asrc,
    const float* __restrict__ adst, int M, int K, int b_mode, int rpb, int noff)
{
    __shared__ unsigned short Ah[128 * LDK];
    __shared__ unsigned short Al[128 * LDK];
    __shared__ unsigned short Bh[128 * LDK];
    __shared__ unsigned short Bl[128 * LDK];

    const int tid  = threadIdx.x;
    const int lane = tid & 63;
    const int w    = tid >> 6;
    const int rw   = w >> 1, cw = w & 1;
    const int m0   = blockIdx.x * 128;
    const int n0   = blockIdx.y * 128;

    floatx4 acc[4][4];
#pragma unroll
    for (int s = 0; s < 4; s++)
#pragma unroll
        for (int t = 0; t < 4; t++) acc[s][t] = (floatx4)0.f;

    const int arow = tid >> 1;
    const int akh  = (tid & 1) * 16;
    const int bc   = tid & 127;
    const int bkh  = (tid >> 7) * 16;
    const int bhead = (n0 + bc) >> 6;
    const int bf    = (n0 + bc) & 63;

    const int afrag0 = (rw * 64 + (lane & 15)) * LDK + (lane >> 4) * 8;
    const int bfrag0 = (cw * 64 + (lane & 15)) * LDK + (lane >> 4) * 8;

    for (int k0 = 0; k0 < K; k0 += 32) {
        __syncthreads();
        {
            const float* ga = A + (size_t)(m0 + arow) * K + k0 + akh;
            const int la = arow * LDK + akh;
            if (k0 + 32 <= K) {
#pragma unroll
                for (int u = 0; u < 4; u++) {
                    float4 v = *(const float4*)(ga + 4 * u);
                    unsigned short h0,h1,h2,h3,l0,l1,l2,l3;
                    split1(v.x,h0,l0); split1(v.y,h1,l1);
                    split1(v.z,h2,l2); split1(v.w,h3,l3);
                    *(uint2*)&Ah[la + 4*u] = make_uint2(pack2(h0,h1), pack2(h2,h3));
                    *(uint2*)&Al[la + 4*u] = make_uint2(pack2(l0,l1), pack2(l2,l3));
                }
            } else {
#pragma unroll
                for (int u = 0; u < 16; u++) {
                    float v = (k0 + akh + u < K) ? ga[u] : 0.f;
                    unsigned short h, l; split1(v, h, l);
                    Ah[la + u] = h; Al[la + u] = l;
                }
            }
        }
        {
            unsigned short hb[16], lb[16];
#pragma unroll
            for (int u = 0; u < 16; u++) {
                int k = k0 + bkh + u;
                float v;
                if (k < K) {
                    size_t gi = b_mode
                        ? (size_t)bhead * (512 * 64) + (size_t)k * 64 + bf
                        : (size_t)k * 512 + n0 + bc;
                    v = Bsrc[gi];
                } else v = 0.f;
                split1(v, hb[u], lb[u]);
            }
            const int lb0 = bc * LDK + bkh;
#pragma unroll
            for (int u = 0; u < 4; u++) {
                *(uint2*)&Bh[lb0 + 4*u] = make_uint2(pack2(hb[4*u],hb[4*u+1]), pack2(hb[4*u+2],hb[4*u+3]));
                *(uint2*)&Bl[lb0 + 4*u] = make_uint2(pack2(lb[4*u],lb[4*u+1]), pack2(lb[4*u+2],lb[4*u+3]));
            }
        }
        __syncthreads();

        bf16x8 ah[4], al[4], bh[4], bl[4];
#pragma unroll
        for (int s = 0; s < 4; s++) {
            ah[s] = *(const bf16x8*)&Ah[afrag0 + s * 16 * LDK];
            al[s] = *(const bf16x8*)&Al[afrag0 + s * 16 * LDK];
        }
#pragma unroll
        for (int t = 0; t < 4; t++) {
            bh[t] = *(const bf16x8*)&Bh[bfrag0 + t * 16 * LDK];
            bl[t] = *(const bf16x8*)&Bl[bfrag0 + t * 16 * LDK];
        }
#pragma unroll
        for (int s = 0; s < 4; s++)
#pragma unroll
            for (int t = 0; t < 4; t++) {
                acc[s][t] = __builtin_amdgcn_mfma_f32_16x16x32_bf16(ah[s], bh[t], acc[s][t], 0, 0, 0);
                acc[s][t] = __builtin_amdgcn_mfma_f32_16x16x32_bf16(ah[s], bl[t], acc[s][t], 0, 0, 0);
                acc[s][t] = __builtin_amdgcn_mfma_f32_16x16x32_bf16(al[s], bh[t], acc[s][t], 0, 0, 0);
            }
    }

    if (b_mode == 0) {
        // fp32 x epilogue (C/D: col=lane&15, row=(lane>>4)*4+reg)
#pragma unroll
        for (int s = 0; s < 4; s++) {
            const int gr0 = m0 + rw * 64 + s * 16 + (lane >> 4) * 4;
#pragma unroll
            for (int r = 0; r < 4; r++) {
                const unsigned grow = gr0 + r;
                const unsigned b = grow / (unsigned)rpb;
                const unsigned rr = grow - b * rpb;
                float* crow = C + ((size_t)b * NN + noff + rr) * HIDD;
#pragma unroll
                for (int t = 0; t < 4; t++) {
                    crow[n0 + cw * 64 + t * 16 + (lane & 15)] = acc[s][t][r];
                }
            }
        }
    } else {
        // Ht fragment-layout split-bf16 epilogue
        const int hd = (n0 + cw * 64) >> 6;
        const int fq = lane & 15;
#pragma unroll
        for (int s = 0; s < 4; s++) {
            const int m_s = m0 + rw * 64 + s * 16 + (lane >> 4) * 4;  // rows m_s..m_s+3
            const unsigned b = (unsigned)m_s / 320u;   // constant over r (m_s%4==0)
            const int jb = m_s - b * 320;              // node j base, mult of 4
            const int ks = jb >> 5;
            const int jg2 = (jb >> 3) & 3;
            const int eb = jb & 7;                     // 0 or 4
            const size_t slab = (size_t)b * 8 + hd;
#pragma unroll
            for (int t = 0; t < 4; t++) {
                unsigned short h0,h1,h2,h3,l0,l1,l2,l3;
                split1(acc[s][t][0],h0,l0); split1(acc[s][t][1],h1,l1);
                split1(acc[s][t][2],h2,l2); split1(acc[s][t][3],h3,l3);
                const size_t base = (((slab * 10 + ks) * 4 + t) * 512
                                     + (size_t)(fq | (jg2 << 4)) * 8) + eb;
                *(uint2*)&Hthi[base] = make_uint2(pack2(h0,h1), pack2(h2,h3));
                *(uint2*)&Htlo[base] = make_uint2(pack2(l0,l1), pack2(l2,l3));
            }
        }
        // ---- fi/fj fold: exact fp32 dot(H_row, a_src/a_dst) per (row, head) --
        float as4[4], ad4[4];
#pragma unroll
        for (int t = 0; t < 4; t++) {
            as4[t] = asrc[hd * 64 + t * 16 + fq];
            ad4[t] = adst[hd * 64 + t * 16 + fq];
        }
#pragma unroll
        for (int s = 0; s < 4; s++) {
            const int m_s = m0 + rw * 64 + s * 16 + (lane >> 4) * 4;
            const unsigned b = (unsigned)m_s / 320u;
            const int jb = m_s - b * 320;
            float4 fi4, fj4;
#pragma unroll
            for (int r = 0; r < 4; r++) {
                float fi = (acc[s][0][r]*as4[0] + acc[s][1][r]*as4[1])
                         + (acc[s][2][r]*as4[2] + acc[s][3][r]*as4[3]);
                float fj = (acc[s][0][r]*ad4[0] + acc[s][1][r]*ad4[1])
                         + (acc[s][2][r]*ad4[2] + acc[s][3][r]*ad4[3]);
#pragma unroll
                for (int d = 1; d < 16; d <<= 1) {
                    fi += __shfl_xor(fi, d);
                    fj += __shfl_xor(fj, d);
                }
                ((float*)&fi4)[r] = fi; ((float*)&fj4)[r] = fj;
            }
            if (fq == 0) {
                const size_t o = ((size_t)b * 8 + hd) * NN + jb;
                *(float4*)&fif_g[o] = fi4;
                *(float4*)&fjf_g[o] = fj4;
            }
        }
    }
}

// ---------------------------------------------------------------------------
// MFMA GAT attention, v4: grid (512, 2) -> 1024 blocks = 4/CU (launch_bounds
// (256,4) caps regs at 128/wave). block-y splits the i dimension: y=0 owns
// ip {0,1,2}, y=1 owns {3,4}. fi/fj come precomputed from gemm_h (no
// pre-pass); scores use me = adj?exp(elog):0 (half the loads, no cndmask).
// Zero barriers/atomics in main loop; per ks: phase1 (scores->A-frags for
// all NIP), phase2 (per nt: load B pair, 3*NIP MFMA).
// ---------------------------------------------------------------------------
template<int IP0, int NIP>
__device__ __forceinline__ void attn_body(
    const unsigned short* __restrict__ Hthi, const unsigned short* __restrict__ Htlo,
    float* __restrict__ xout, int apply_elu, float* fjs, float* ls)
{
    const int bh = blockIdx.x;          // b*8 + hd
    const int hd = bh & 7, b = bh >> 3;
    const int tid = threadIdx.x, lane = tid & 63, w = tid >> 6;
    const int fq = lane & 15, jg = lane >> 4;

    for (int r = tid; r < NN; r += 256) fjs[r] = fjf_g[bh * NN + r];

    float fir[NIP];
#pragma unroll
    for (int ip = 0; ip < NIP; ip++)
        fir[ip] = fif_g[bh * NN + (IP0 + ip) * 64 + (w << 4) + fq];
    __syncthreads();

    floatx4 acc[NIP][4];
#pragma unroll
    for (int ip = 0; ip < NIP; ip++)
#pragma unroll
        for (int nt = 0; nt < 4; nt++) acc[ip][nt] = (floatx4)0.f;
    float lacc[NIP];
#pragma unroll
    for (int ip = 0; ip < NIP; ip++) lacc[ip] = 0.f;

    for (int ks = 0; ks < 10; ks++) {
        const int j8 = ks * 32 + jg * 8;
        const float4 fj0 = *(const float4*)&fjs[j8];
        const float4 fj1 = *(const float4*)&fjs[j8 + 4];

        // ---- phase 1: scores -> exp*me -> split-bf16 A-frags ----
        bf16x8 ahh[NIP], all[NIP];
#pragma unroll
        for (int ip = 0; ip < NIP; ip++) {
            const int i = (IP0 + ip) * 64 + (w << 4) + fq;
            const float fiv = fir[ip];
            const unsigned g = (unsigned)i * NN + j8;
            const float4 m0 = *(const float4*)&me_g[g];
            const float4 m1 = *(const float4*)&me_g[g + 4];
            float p[8];
            {
                float s;
                s = fiv + fj0.x; s = fmaxf(s, 0.2f*s); p[0] = __expf(s) * m0.x;
                s = fiv + fj0.y; s = fmaxf(s, 0.2f*s); p[1] = __expf(s) * m0.y;
                s = fiv + fj0.z; s = fmaxf(s, 0.2f*s); p[2] = __expf(s) * m0.z;
                s = fiv + fj0.w; s = fmaxf(s, 0.2f*s); p[3] = __expf(s) * m0.w;
                s = fiv + fj1.x; s = fmaxf(s, 0.2f*s); p[4] = __expf(s) * m1.x;
                s = fiv + fj1.y; s = fmaxf(s, 0.2f*s); p[5] = __expf(s) * m1.y;
                s = fiv + fj1.z; s = fmaxf(s, 0.2f*s); p[6] = __expf(s) * m1.z;
                s = fiv + fj1.w; s = fmaxf(s, 0.2f*s); p[7] = __expf(s) * m1.w;
            }
            lacc[ip] += ((p[0]+p[1]) + (p[2]+p[3])) + ((p[4]+p[5]) + (p[6]+p[7]));

            unsigned short ph[8], pl[8];
#pragma unroll
            for (int e = 0; e < 8; e++) split1(p[e], ph[e], pl[e]);
            union { uint4 u; bf16x8 v; } ua, ul;
            ua.u = make_uint4(pack2(ph[0],ph[1]), pack2(ph[2],ph[3]),
                              pack2(ph[4],ph[5]), pack2(ph[6],ph[7]));
            ul.u = make_uint4(pack2(pl[0],pl[1]), pack2(pl[2],pl[3]),
                              pack2(pl[4],pl[5]), pack2(pl[6],pl[7]));
            ahh[ip] = ua.v; all[ip] = ul.v;
        }

        // ---- phase 2: per f-tile, load B pair then 3*NIP MFMAs ----
#pragma unroll
        for (int nt = 0; nt < 4; nt++) {
            const unsigned off = (((unsigned)bh * 10 + ks) * 4 + nt) * 512 + (unsigned)lane * 8;
            const bf16x8 bhf = *(const bf16x8*)&Hthi[off];
            const bf16x8 blf = *(const bf16x8*)&Htlo[off];
#pragma unroll
            for (int ip = 0; ip < NIP; ip++) {
                acc[ip][nt] = __builtin_amdgcn_mfma_f32_16x16x32_bf16(ahh[ip], bhf, acc[ip][nt], 0, 0, 0);
                acc[ip][nt] = __builtin_amdgcn_mfma_f32_16x16x32_bf16(ahh[ip], blf, acc[ip][nt], 0, 0, 0);
                acc[ip][nt] = __builtin_amdgcn_mfma_f32_16x16x32_bf16(all[ip], bhf, acc[ip][nt], 0, 0, 0);
            }
        }
    }

    // ---- l reduction: sum over the 4 jg lanes holding the same i ----
#pragma unroll
    for (int ip = 0; ip < NIP; ip++) {
        float l = lacc[ip];
        l += __shfl_xor(l, 16);
        l += __shfl_xor(l, 32);
        if (jg == 0) ls[(IP0 + ip) * 64 + (w << 4) + fq] = l;
    }
    __syncthreads();

    // ---- epilogue: D col(f)=lane&15, row(i)=(lane>>4)*4+reg ----
#pragma unroll
    for (int ip = 0; ip < NIP; ip++) {
        const int ib = ((IP0 + ip) * 4 + w) * 16 + jg * 4;
#pragma unroll
        for (int r = 0; r < 4; r++) {
            const float lv = ls[ib + r];
            const float inv = (lv > 0.f) ? 1.f / lv : 0.f;   // fully-masked row -> 0
            float* orow = xout + ((size_t)(b * NN + ib + r)) * HIDD + hd * 64;
#pragma unroll
            for (int nt = 0; nt < 4; nt++) {
                float vv = acc[ip][nt][r] * inv;
                if (apply_elu) vv = (vv > 0.f) ? vv : __expf(vv) - 1.f;
                orow[nt * 16 + fq] = vv;
            }
        }
    }
}

__global__ __launch_bounds__(256, 4) void attn_mfma(
    const unsigned short* __restrict__ Hthi, const unsigned short* __restrict__ Htlo,
    float* __restrict__ xout, int apply_elu)
{
    __shared__ float fjs[NN];
    __shared__ float ls[NN];
    if (blockIdx.y == 0) attn_body<0, 3>(Hthi, Htlo, xout, apply_elu, fjs, ls);
    else                 attn_body<3, 2>(Hthi, Htlo, xout, apply_elu, fjs, ls);
}

// ---------------------------------------------------------------------------
// Workspace: Ht hi plane 20,971,520 B + lo plane 20,971,520 B (== out bytes).
// me/fi/fj live in __device__ globals (stream-ordered writes before reads).
// Flow: build_me; proj -> d_out (x); per layer: gemm_h reads x, writes
// Ht(ws)+fi/fj; attn reads Ht/me/fi/fj, writes x'/final to d_out.
// ---------------------------------------------------------------------------
extern "C" void kernel_launch(void* const* d_in, const int* in_sizes, int n_in,
                              void* d_out, int out_size, void* d_ws, size_t ws_size,
                              hipStream_t stream)
{
    (void)in_sizes; (void)n_in; (void)out_size; (void)ws_size;
    const float* text     = (const float*)d_in[0];
    const float* visual   = (const float*)d_in[1];
    const float* acoustic = (const float*)d_in[2];
    const int*   adj      = (const int*)d_in[3];
    const float* Wt       = (const float*)d_in[4];
    const float* Wv       = (const float*)d_in[5];
    const float* Wa       = (const float*)d_in[6];
    const float* Wg       = (const float*)d_in[7];
    const float* a_src    = (const float*)d_in[8];
    const float* a_dst    = (const float*)d_in[9];
    const float* elog     = (const float*)d_in[10];

    float* xbuf = (float*)d_out;
    unsigned short* Hthi = (unsigned short*)d_ws;
    unsigned short* Htlo = Hthi + (size_t)512 * 10 * 4 * 512;   // 10,485,760 shorts

    build_me<<<NN * NN / 1024, 256, 0, stream>>>(adj, elog);

    gemm_mfma<<<dim3((BB*NT)/128, 4), 256, 0, stream>>>(text,     Wt, xbuf, nullptr, nullptr, nullptr, nullptr, BB*NT, 768, 0, NT, 0);
    gemm_mfma<<<dim3((BB*NV)/128, 4), 256, 0, stream>>>(visual,   Wv, xbuf, nullptr, nullptr, nullptr, nullptr, BB*NV,  47, 0, NV, NT);
    gemm_mfma<<<dim3((BB*NA)/128, 4), 256, 0, stream>>>(acoustic, Wa, xbuf, nullptr, nullptr, nullptr, nullptr, BB*NA,  74, 0, NA, NT + NV);

    for (int l = 0; l < 2; l++) {
        const float* Wg_l = Wg + (size_t)l * NHEAD * HIDD * FD;
        gemm_mfma<<<dim3((BB*NN)/128, 4), 256, 0, stream>>>(xbuf, Wg_l, nullptr, Hthi, Htlo,
            a_src + l * NHEAD * FD, a_dst + l * NHEAD * FD, BB*NN, HIDD, 1, NN, 0);
        attn_mfma<<<dim3(BB * NHEAD, 2), 256, 0, stream>>>(
            Hthi, Htlo, xbuf, (l == 0) ? 1 : 0);
    }
}